// Round 4
// baseline (468.273 us; speedup 1.0000x reference)
//
#include <hip/hip_runtime.h>
#include <stdint.h>

#define Bsz   256
#define Tlen  1024
#define Vocab 128
#define Hdim  128
#define NTHR  256
#define WTN   ((Vocab - 1) * Hdim)   // 127*128 = 16256 floats

// h stored as f16 in LDS: 4 chunks of 16 dwords (32 halves) at 20-dword
// stride (80 B). Chunk bases land on banks {0,20,8,28}: the four distinct
// per-j addresses of each b128 read phase hit disjoint bank quads.
#define CHD   20                     // chunk stride in dwords
#define HBUFI (4 * CHD)              // dwords per buffer = 80

typedef _Float16 half2_t __attribute__((ext_vector_type(2)));

__device__ __forceinline__ float tanh_fast(float x) {
    // tanh(x) = 1 - 2/(exp2(2x*log2e)+1); exact limits at +-inf
    float e = __builtin_amdgcn_exp2f(x * 2.885390081777927f);
    return 1.0f - 2.0f * __builtin_amdgcn_rcpf(e + 1.0f);
}

// quad-local DPP reductions (pure VALU, no LDS pipe)
__device__ __forceinline__ float dpp_xor1(float s) {
    return __int_as_float(__builtin_amdgcn_mov_dpp(__float_as_int(s), 0xB1, 0xF, 0xF, true));  // quad_perm(1,0,3,2)
}
__device__ __forceinline__ float dpp_xor2(float s) {
    return __int_as_float(__builtin_amdgcn_mov_dpp(__float_as_int(s), 0x4E, 0xF, 0xF, true));  // quad_perm(2,3,0,1)
}

// Tiny prep: transpose W_ih (H x V-1) -> wt (V-1 x H).
__global__ __launch_bounds__(256) void transpose_kernel(
    const float* __restrict__ W_ih, float* __restrict__ wt)
{
    int idx = blockIdx.x * 256 + threadIdx.x;
    if (idx < WTN) {
        int h = idx / (Vocab - 1);
        int f = idx - h * (Vocab - 1);
        wt[f * Hdim + h] = W_ih[idx];   // wt[f][h] = W_ih[h][f]
    }
}

// One block (256 thr, 4 waves = 1/SIMD) per sequence. Quad q=tid>>2 owns
// outputs {2q, 2q+1}; lane j=tid&3 covers k in [32j,32j+32).
// v_dot2_f32_f16 dep-latency is ~20 cyc (R2/R3 residual analysis), so the
// dot is split into 8 accumulators (4 chains x 4 links per output) + a
// 2-level add tree. pre+bias is seeded into chain c00/c10 of lane j==0
// (computed the previous iteration, off the critical path), so the tail is
// tree -> 2 DPP reduce adds -> tanh -> pack -> write. One barrier per step.
__global__ __launch_bounds__(NTHR, 1) void rnn_kernel(
    const float* __restrict__ x, const float* __restrict__ wt,
    const float* __restrict__ W_hh,
    const float* __restrict__ b_ih, const float* __restrict__ b_hh,
    const float* __restrict__ W_out, const float* __restrict__ b_out,
    float* __restrict__ out)
{
    __shared__ float wt_s[WTN];                    // 65 KB pre gather table
    __shared__ int   syms[Tlen];                   // 4 KB
    __shared__ __align__(16) int hbuf[2][HBUFI];   // f16 h, double-buffered
    __shared__ int   len_sh;

    const int tid = threadIdx.x;
    const int b   = blockIdx.x;
    const int g   = tid >> 2;   // quad 0..63, owns outputs 2g, 2g+1
    const int j   = tid & 3;    // K-chunk index within quad
    const bool jz = (j == 0);

    if (tid == 0) len_sh = Tlen;
    if (tid < 2 * HBUFI) ((int*)hbuf)[tid] = 0;    // h0 = 0 (incl. pads)

    // W_hh rows 2g,2g+1, cols [32j,32j+32) -> 32 packed f16x2 registers
    int wp[32];
    #pragma unroll
    for (int r = 0; r < 2; r++) {
        const float4* wrow = (const float4*)(W_hh + (2 * g + r) * Hdim + 32 * j);
        #pragma unroll
        for (int q4 = 0; q4 < 8; q4++) {
            float4 t4 = wrow[q4];
            wp[r * 16 + q4 * 2 + 0] = __builtin_bit_cast(int, __builtin_amdgcn_cvt_pkrtz(t4.x, t4.y));
            wp[r * 16 + q4 * 2 + 1] = __builtin_bit_cast(int, __builtin_amdgcn_cvt_pkrtz(t4.z, t4.w));
        }
    }
    const float bias0 = b_ih[2 * g]     + b_hh[2 * g];
    const float bias1 = b_ih[2 * g + 1] + b_hh[2 * g + 1];

    // stage wt -> LDS, coalesced float4
    {
        const float4* src = (const float4*)wt;
        float4* dst = (float4*)wt_s;
        for (int k = tid; k < WTN / 4; k += NTHR) dst[k] = src[k];
    }

    // Decode this block's one-hot rows (512 KB, float4 coalesced, 8-deep
    // batches to keep HBM pipelined at 4 waves/CU).
    {
        const float4* xb = (const float4*)(x + (size_t)b * Tlen * Vocab);
        const int R4 = Tlen * Vocab / 4;           // 32768
        for (int base = 0; base < R4; base += NTHR * 8) {   // 16 batches
            float4 v[8];
            #pragma unroll
            for (int i = 0; i < 8; i++) v[i] = xb[base + NTHR * i + tid];
            #pragma unroll
            for (int i = 0; i < 8; i++) {
                int k = base + NTHR * i + tid;
                int c = -1;
                if      (v[i].x > 0.5f) c = 0;
                else if (v[i].y > 0.5f) c = 1;
                else if (v[i].z > 0.5f) c = 2;
                else if (v[i].w > 0.5f) c = 3;
                if (c >= 0) syms[k >> 5] = ((k & 31) << 2) + c;  // 32 float4/row
            }
        }
    }
    __syncthreads();

    // length = first t with sym==0 (pad), else Tlen
    {
        int lm = Tlen;
        for (int k = tid; k < Tlen; k += NTHR)
            if (syms[k] == 0 && k < lm) lm = k;
        if (lm < Tlen) atomicMin(&len_sh, lm);
    }
    __syncthreads();
    const int len = len_sh;

    // pre pipeline: float2 (elements 2g,2g+1) for t ready, t+1 in flight,
    // symbol for t+2 in register. All quad lanes same index -> broadcast.
    const float2* wt2 = (const float2*)wt_s;   // pair index: (sym-1)*64 + g
    float2 pre_v = {0.0f, 0.0f}, p_t1 = {0.0f, 0.0f};
    int s_t2 = 1;
    if (len > 0) pre_v = wt2[(syms[0] - 1) * 64 + g];
    if (len > 1) p_t1  = wt2[(syms[1] - 1) * 64 + g];
    if (len > 2) s_t2  = syms[2];

    // chain seeds for step t: (pre+bias) gated to lane j==0 so the quad
    // reduce counts it exactly once; recomputed each iteration off-path.
    float sel0 = jz ? pre_v.x + bias0 : 0.0f;
    float sel1 = jz ? pre_v.y + bias1 : 0.0f;

    const char* hb0 = (const char*)hbuf[0];
    const char* hb1 = (const char*)hbuf[1];
    const int roff = j * (CHD * 4);                 // 80 B per chunk
    const int widx = CHD * (g >> 4) + (g & 15);     // dword slot of pair g

    for (int t = 0; t < len; t++) {
        // h reads first: start the ~130-cyc LDS latency immediately
        const char* hb = (t & 1) ? hb1 : hb0;
        uint4 r0 = *(const uint4*)(hb + roff);
        uint4 r1 = *(const uint4*)(hb + roff + 16);
        uint4 r2 = *(const uint4*)(hb + roff + 32);
        uint4 r3 = *(const uint4*)(hb + roff + 48);

        float2 p_t2 = wt2[(s_t2 - 1) * 64 + g];   // LDS b64 gather for t+2
        int   s_t3 = (t + 3 < len) ? syms[t + 3] : 1;

        // keep packed W pinned (cheap at this register pressure)
        #pragma unroll
        for (int k = 0; k < 32; k += 8)
            asm volatile("" : "+v"(wp[k]), "+v"(wp[k+1]), "+v"(wp[k+2]), "+v"(wp[k+3]),
                              "+v"(wp[k+4]), "+v"(wp[k+5]), "+v"(wp[k+6]), "+v"(wp[k+7]));

        unsigned hr[16] = {r0.x, r0.y, r0.z, r0.w, r1.x, r1.y, r1.z, r1.w,
                           r2.x, r2.y, r2.z, r2.w, r3.x, r3.y, r3.z, r3.w};

        // 8 chains x 4 links (dot2 dep-lat ~20 -> chain ~80 vs 160 for 8-link)
        float c00 = sel0, c01 = 0.0f, c02 = 0.0f, c03 = 0.0f;
        float c10 = sel1, c11 = 0.0f, c12 = 0.0f, c13 = 0.0f;
        #pragma unroll
        for (int d = 0; d < 4; d++) {
            half2_t h0 = __builtin_bit_cast(half2_t, hr[d]);
            half2_t h1 = __builtin_bit_cast(half2_t, hr[4 + d]);
            half2_t h2 = __builtin_bit_cast(half2_t, hr[8 + d]);
            half2_t h3 = __builtin_bit_cast(half2_t, hr[12 + d]);
            c00 = __builtin_amdgcn_fdot2(h0, __builtin_bit_cast(half2_t, wp[d]),      c00, false);
            c01 = __builtin_amdgcn_fdot2(h1, __builtin_bit_cast(half2_t, wp[4 + d]),  c01, false);
            c02 = __builtin_amdgcn_fdot2(h2, __builtin_bit_cast(half2_t, wp[8 + d]),  c02, false);
            c03 = __builtin_amdgcn_fdot2(h3, __builtin_bit_cast(half2_t, wp[12 + d]), c03, false);
            c10 = __builtin_amdgcn_fdot2(h0, __builtin_bit_cast(half2_t, wp[16 + d]), c10, false);
            c11 = __builtin_amdgcn_fdot2(h1, __builtin_bit_cast(half2_t, wp[20 + d]), c11, false);
            c12 = __builtin_amdgcn_fdot2(h2, __builtin_bit_cast(half2_t, wp[24 + d]), c12, false);
            c13 = __builtin_amdgcn_fdot2(h3, __builtin_bit_cast(half2_t, wp[28 + d]), c13, false);
        }
        float a0 = (c00 + c01) + (c02 + c03);
        float a1 = (c10 + c11) + (c12 + c13);
        a0 += dpp_xor1(a0); a1 += dpp_xor1(a1);
        a0 += dpp_xor2(a0); a1 += dpp_xor2(a1);   // quad-invariant full pre-act

        // all 4 quad lanes compute tanh (no divergence); lane j==0 writes
        float h0v = tanh_fast(a0);
        float h1v = tanh_fast(a1);
        int pk = __builtin_bit_cast(int, __builtin_amdgcn_cvt_pkrtz(h0v, h1v));
        if (jz) ((int*)hbuf[(t + 1) & 1])[widx] = pk;

        // rotate pre pipeline + next-step seeds (all off the critical path)
        pre_v = p_t1; p_t1 = p_t2; s_t2 = s_t3;
        sel0 = jz ? pre_v.x + bias0 : 0.0f;
        sel1 = jz ? pre_v.y + bias1 : 0.0f;
        __syncthreads();
    }

    // epilogue: hidden state + softmax head
    const _Float16* hf = (const _Float16*)hbuf[len & 1];
    #define HGET(e) ((float)hf[40 * ((e) >> 5) + (((e) >> 1) & 15) * 2 + ((e) & 1)])
    if (tid < Hdim)
        out[2 * Bsz + b * Hdim + tid] = HGET(tid);
    if (tid < 64) {
        float h0 = HGET(tid);
        float h1 = HGET(tid + 64);
        float p0 = W_out[tid] * h0 + W_out[64 + tid] * h1;
        float p1 = W_out[128 + tid] * h0 + W_out[192 + tid] * h1;
        #pragma unroll
        for (int off = 32; off > 0; off >>= 1) {
            p0 += __shfl_down(p0, off, 64);
            p1 += __shfl_down(p1, off, 64);
        }
        if (tid == 0) {
            float l0 = p0 + b_out[0], l1 = p1 + b_out[1];
            float m  = fmaxf(l0, l1);
            float e0 = __expf(l0 - m), e1 = __expf(l1 - m);
            float d  = e0 + e1;
            out[b * 2 + 0] = e0 / d;
            out[b * 2 + 1] = e1 / d;
        }
    }
    #undef HGET
}

extern "C" void kernel_launch(void* const* d_in, const int* in_sizes, int n_in,
                              void* d_out, int out_size, void* d_ws, size_t ws_size,
                              hipStream_t stream) {
    const float* x     = (const float*)d_in[0];
    const float* W_ih  = (const float*)d_in[1];
    const float* W_hh  = (const float*)d_in[2];
    const float* b_ih  = (const float*)d_in[3];
    const float* b_hh  = (const float*)d_in[4];
    const float* W_out = (const float*)d_in[5];
    const float* b_out = (const float*)d_in[6];
    float* out = (float*)d_out;

    float* wt = (float*)d_ws;  // (V-1) x H floats = 65 KB

    const int NTRN = (WTN + 255) / 256;  // 64 blocks
    transpose_kernel<<<NTRN, 256, 0, stream>>>(W_ih, wt);
    rnn_kernel<<<Bsz, NTHR, 0, stream>>>(x, wt, W_hh, b_ih, b_hh, W_out, b_out, out);
}